// Round 6
// baseline (3547.652 us; speedup 1.0000x reference)
//
#include <hip/hip_runtime.h>
#include <math.h>

#define B_   128
#define T_   288
#define U_   256
#define MT   (B_*T_)
#define EPSF 1e-6f

typedef _Float16 h2_t  __attribute__((ext_vector_type(2)));
typedef _Float16 hfv8  __attribute__((ext_vector_type(8)));
typedef float    f32x4 __attribute__((ext_vector_type(4)));

__device__ __forceinline__ _Float16 f2h(float x) { return (_Float16)x; }

// ---------------- fp32 GEMM (only for d0: K=16) ----------------
__global__ __launch_bounds__(256) void gemm_f32_kernel(
    const float* __restrict__ A, const float* __restrict__ Bm,
    float* __restrict__ C, const float* __restrict__ bias,
    int M, int N, int K, int lda, int ldb, int ldc)
{
  __shared__ float As[16][68];
  __shared__ float Bs[16][68];
  const int tid = threadIdx.x;
  const int tx = tid & 15, ty = tid >> 4;
  const int rowBase = blockIdx.y * 64, colBase = blockIdx.x * 64;
  float acc[4][4] = {};
  const int lr = tid >> 2, lk = (tid & 3) << 2;
  for (int k0 = 0; k0 < K; k0 += 16) {
    {
      float4 a4 = {0,0,0,0};
      int ar = rowBase + lr;
      if (ar < M) a4 = *(const float4*)(A + (long)ar*lda + k0 + lk);
      As[lk+0][lr]=a4.x; As[lk+1][lr]=a4.y; As[lk+2][lr]=a4.z; As[lk+3][lr]=a4.w;
    }
    {
      int bk = tid >> 4, bn4 = (tid & 15) << 2;
      float4 b4 = {0,0,0,0};
      if (colBase + bn4 < N) b4 = *(const float4*)(Bm + (long)(k0+bk)*ldb + colBase + bn4);
      *(float4*)(&Bs[bk][bn4]) = b4;
    }
    __syncthreads();
    #pragma unroll
    for (int k = 0; k < 16; ++k) {
      float4 av = *(const float4*)(&As[k][ty<<2]);
      float4 bv = *(const float4*)(&Bs[k][tx<<2]);
      acc[0][0]+=av.x*bv.x; acc[0][1]+=av.x*bv.y; acc[0][2]+=av.x*bv.z; acc[0][3]+=av.x*bv.w;
      acc[1][0]+=av.y*bv.x; acc[1][1]+=av.y*bv.y; acc[1][2]+=av.y*bv.z; acc[1][3]+=av.y*bv.w;
      acc[2][0]+=av.z*bv.x; acc[2][1]+=av.z*bv.y; acc[2][2]+=av.z*bv.z; acc[2][3]+=av.z*bv.w;
      acc[3][0]+=av.w*bv.x; acc[3][1]+=av.w*bv.y; acc[3][2]+=av.w*bv.z; acc[3][3]+=av.w*bv.w;
    }
    __syncthreads();
  }
  const int cn = colBase + (tx << 2);
  if (cn < N) {
    float4 bb = {0,0,0,0};
    if (bias) bb = *(const float4*)(bias + cn);
    #pragma unroll
    for (int i = 0; i < 4; ++i) {
      int r = rowBase + (ty << 2) + i;
      if (r < M) {
        float4 v;
        v.x = acc[i][0]+bb.x; v.y = acc[i][1]+bb.y; v.z = acc[i][2]+bb.z; v.w = acc[i][3]+bb.w;
        *(float4*)(C + (long)r*ldc + cn) = v;
      }
    }
  }
}

// ---------------- f16 MFMA GEMM: C[M,N] = A[M,K] @ Bt[N,K]^T + bias ----------------
// 128x128 tile, 256 thr (4 waves), BK=32. SYNCHRONOUS staging (vector load ->
// ds_write_b128) — no global_load_lds (replay-race hardening).
template<int OUTF16>
__global__ __launch_bounds__(256) void gemm_bt_f16_kernel(
    const _Float16* __restrict__ A, const _Float16* __restrict__ Bt,
    float* __restrict__ Cf, _Float16* __restrict__ Ch,
    const float* __restrict__ bias, int M, int N, int K)
{
  __shared__ _Float16 sA[128*32];
  __shared__ _Float16 sB[128*32];
  const int tid = threadIdx.x;
  const int w = tid >> 6, lane = tid & 63, quad = lane >> 4, l15 = lane & 15;
  const int rowBase = blockIdx.y * 128, colBase = blockIdx.x * 128;
  const int wRow = (w & 1) * 64, wCol = (w >> 1) * 64;
  const int sr = tid >> 2;          // 0..63
  const int scol = (tid & 3) * 8;   // 0,8,16,24

  f32x4 acc[4][4];
  #pragma unroll
  for (int i = 0; i < 4; ++i)
    #pragma unroll
    for (int j = 0; j < 4; ++j) acc[i][j] = (f32x4){0.f,0.f,0.f,0.f};

  for (int k0 = 0; k0 < K; k0 += 32) {
    #pragma unroll
    for (int c = 0; c < 2; ++c) {
      int r = c*64 + sr;
      hfv8 va = *(const hfv8*)(A  + (long)(rowBase + r)*K + k0 + scol);
      hfv8 vb = *(const hfv8*)(Bt + (long)(colBase + r)*K + k0 + scol);
      *(hfv8*)&sA[r*32 + scol] = va;
      *(hfv8*)&sB[r*32 + scol] = vb;
    }
    __syncthreads();
    hfv8 af[4], bfr[4];
    #pragma unroll
    for (int mt = 0; mt < 4; ++mt)
      af[mt] = *(const hfv8*)&sA[(wRow + mt*16 + l15)*32 + quad*8];
    #pragma unroll
    for (int nt = 0; nt < 4; ++nt)
      bfr[nt] = *(const hfv8*)&sB[(wCol + nt*16 + l15)*32 + quad*8];
    #pragma unroll
    for (int mt = 0; mt < 4; ++mt)
      #pragma unroll
      for (int nt = 0; nt < 4; ++nt)
        acc[mt][nt] = __builtin_amdgcn_mfma_f32_16x16x32_f16(af[mt], bfr[nt], acc[mt][nt], 0, 0, 0);
    __syncthreads();
  }
  #pragma unroll
  for (int nt = 0; nt < 4; ++nt) {
    int col = colBase + wCol + nt*16 + l15;
    float bv = bias ? bias[col] : 0.f;
    #pragma unroll
    for (int mt = 0; mt < 4; ++mt)
      #pragma unroll
      for (int r = 0; r < 4; ++r) {
        int row = rowBase + wRow + mt*16 + quad*4 + r;
        float v = acc[mt][nt][r] + bv;
        if (OUTF16) Ch[(long)row*N + col] = f2h(v);
        else        Cf[(long)row*N + col] = v;
      }
  }
}

// ---------------- transpose + f32->f16: in[K,N] -> out[N,K] ----------------
__global__ __launch_bounds__(256) void tconv_kernel(
    const float* __restrict__ in, _Float16* __restrict__ out, int K, int N)
{
  int idx = blockIdx.x*256 + threadIdx.x;
  if (idx < K*N) {
    int k = idx / N, n = idx - k*N;
    out[(long)n*K + k] = f2h(in[idx]);
  }
}

__global__ __launch_bounds__(256) void catbias_kernel(
    const float* __restrict__ bq, const float* __restrict__ bk,
    const float* __restrict__ bv, float* __restrict__ outb)
{
  int i = blockIdx.x*256 + threadIdx.x;
  if (i < 768) outb[i] = (i < 256) ? bq[i] : ((i < 512) ? bk[i-256] : bv[i-512]);
}

// ---------------- LayerNorm over 256 cols, dual f32/f16 output ----------------
__global__ __launch_bounds__(256) void ln256_kernel(
    const float* __restrict__ in, const float* __restrict__ skip_pre,
    const float* __restrict__ skip_post,
    const float* __restrict__ s, const float* __restrict__ b,
    float* __restrict__ outf, _Float16* __restrict__ outh)
{
  __shared__ float sb[4];
  long row = blockIdx.x;
  int tid = threadIdx.x;
  long idx = row*256 + tid;
  float v = in[idx];
  if (skip_pre) v += skip_pre[idx];
  float m = v;
  for (int o = 32; o; o >>= 1) m += __shfl_xor(m, o);
  if ((tid & 63) == 0) sb[tid >> 6] = m;
  __syncthreads();
  m = (sb[0]+sb[1]+sb[2]+sb[3]) * (1.f/256.f);
  __syncthreads();
  float d = v - m;
  float var = d*d;
  for (int o = 32; o; o >>= 1) var += __shfl_xor(var, o);
  if ((tid & 63) == 0) sb[tid >> 6] = var;
  __syncthreads();
  var = (sb[0]+sb[1]+sb[2]+sb[3]) * (1.f/256.f);
  float y = d * rsqrtf(var + EPSF) * s[tid] + b[tid];
  if (skip_post) y += skip_post[idx];
  if (outf) outf[idx] = y;
  if (outh) outh[idx] = f2h(y);
}

// ---------------- GRU scan: R1 structure (1024 thr), f16 gate inputs ----------------
__global__ __launch_bounds__(1024, 1) void gru_scan_kernel(
    const _Float16* __restrict__ xg, // [B,T,768] f16
    const float* __restrict__ Wh,    // [256,768]
    const float* __restrict__ bhn,   // [256]
    float* __restrict__ g)           // [B,T,256]
{
  const int b   = blockIdx.x;
  const int tid = threadIdx.x;
  const int u   = tid & 255;
  const int kq  = tid >> 8;

  __shared__ float hf[256];
  __shared__ h2_t  hh2s[128];
  __shared__ float part[4][3][256];

  h2_t wr[32], wz[32], wn[32];
  #pragma unroll
  for (int r = 0; r < 32; ++r) {
    const float* p0 = Wh + (long)(kq*64 + 2*r)*768 + u;
    const float* p1 = p0 + 768;
    h2_t a; a.x = (_Float16)p0[0];   a.y = (_Float16)p1[0];   wr[r] = a;
    h2_t c; c.x = (_Float16)p0[256]; c.y = (_Float16)p1[256]; wz[r] = c;
    h2_t d; d.x = (_Float16)p0[512]; d.y = (_Float16)p1[512]; wn[r] = d;
  }
  float bn = (kq == 0) ? bhn[u] : 0.f;
  if (tid < 256) hf[tid] = 0.f;
  if (tid < 128) { h2_t zz; zz.x = (_Float16)0.f; zz.y = (_Float16)0.f; hh2s[tid] = zz; }
  __syncthreads();

  const _Float16* xgb = xg + (long)b*T_*768;
  float* gb = g + (long)b*T_*256;

  for (int t = 0; t < T_; ++t) {
    float xr = 0.f, xz = 0.f, xn = 0.f;
    if (kq == 0) {
      const _Float16* xt = xgb + (long)t*768;
      xr = (float)xt[u]; xz = (float)xt[u+256]; xn = (float)xt[u+512];
    }
    float ar = 0.f, az = 0.f, an = 0.f;
    #pragma unroll
    for (int r = 0; r < 32; ++r) {
      h2_t hv = hh2s[kq*32 + r];
      ar = __builtin_amdgcn_fdot2(hv, wr[r], ar, false);
      az = __builtin_amdgcn_fdot2(hv, wz[r], az, false);
      an = __builtin_amdgcn_fdot2(hv, wn[r], an, false);
    }
    part[kq][0][u] = ar; part[kq][1][u] = az; part[kq][2][u] = an;
    __syncthreads();
    if (kq == 0) {
      float hr = part[0][0][u]+part[1][0][u]+part[2][0][u]+part[3][0][u] + xr;
      float hz = part[0][1][u]+part[1][1][u]+part[2][1][u]+part[3][1][u] + xz;
      float hn = part[0][2][u]+part[1][2][u]+part[2][2][u]+part[3][2][u];
      float rr = 1.f / (1.f + __expf(-hr));
      float z  = 1.f / (1.f + __expf(-hz));
      float nx = xn + rr * (hn + bn);
      float e2 = __expf(2.f * nx);
      float nv = (e2 - 1.f) / (e2 + 1.f);
      float hnew = (1.f - z) * nv + z * hf[u];
      hf[u] = hnew;
      ((_Float16*)hh2s)[u] = (_Float16)hnew;
      gb[(long)t*256 + u] = hnew;
    }
    __syncthreads();
  }
}

// ---------------- SIMPLE VALU attention ----------------
__global__ __launch_bounds__(256) void attn_simple_kernel(
    const _Float16* __restrict__ qkv,  // [B*T,768] (q|k|v)
    _Float16* __restrict__ ao)         // [B*T,256]
{
  __shared__ _Float16 Kh[T_*64];
  __shared__ float qrow[64];
  __shared__ float sc[T_];
  __shared__ float red[4];
  __shared__ float osum[4][64];
  const int bx = blockIdx.x;
  const int bh = bx >> 2, qc = bx & 3;
  const int b = bh >> 2, h = bh & 3;
  const int tid = threadIdx.x;
  const _Float16* base = qkv + (long)b*T_*768;

  for (int idx = tid; idx < T_*64; idx += 256) {
    int t = idx >> 6, d = idx & 63;
    Kh[idx] = base[(long)t*768 + 256 + h*64 + d];
  }
  __syncthreads();

  const int d_ = tid & 63, part = tid >> 6;
  for (int q = qc*72; q < qc*72 + 72; ++q) {
    if (tid < 64) qrow[tid] = (float)base[(long)q*768 + h*64 + tid];
    __syncthreads();
    for (int t = tid; t < T_; t += 256) {
      float s = 0.f;
      for (int d = 0; d < 64; ++d) s += qrow[d] * (float)Kh[t*64 + d];
      sc[t] = s * 0.125f;
    }
    __syncthreads();
    float lm = -1e30f;
    for (int t = tid; t < T_; t += 256) lm = fmaxf(lm, sc[t]);
    for (int o = 32; o; o >>= 1) lm = fmaxf(lm, __shfl_xor(lm, o));
    if ((tid & 63) == 0) red[tid >> 6] = lm;
    __syncthreads();
    float mx = fmaxf(fmaxf(red[0], red[1]), fmaxf(red[2], red[3]));
    __syncthreads();
    float ls = 0.f;
    for (int t = tid; t < T_; t += 256) { float e = __expf(sc[t] - mx); sc[t] = e; ls += e; }
    for (int o = 32; o; o >>= 1) ls += __shfl_xor(ls, o);
    if ((tid & 63) == 0) red[tid >> 6] = ls;
    __syncthreads();
    float inv = 1.f / (red[0] + red[1] + red[2] + red[3]);
    float acc = 0.f;
    const _Float16* vb = base + 512 + h*64 + d_;
    for (int t = part*72; t < part*72 + 72; ++t)
      acc += sc[t] * (float)vb[(long)t*768];
    osum[part][d_] = acc;
    __syncthreads();
    if (tid < 64) {
      float ov = (osum[0][tid] + osum[1][tid] + osum[2][tid] + osum[3][tid]) * inv;
      ao[((long)b*T_ + q)*256 + h*64 + tid] = f2h(ov);
    }
    __syncthreads();
  }
}

// ---------------- mean over T ----------------
__global__ __launch_bounds__(256) void meanT_kernel(
    const float* __restrict__ x, float* __restrict__ xm)
{
  int b = blockIdx.x, u = threadIdx.x;
  const float* p = x + (long)b*T_*U_ + u;
  float s = 0.f;
  for (int t = 0; t < T_; ++t) s += p[(long)t*U_];
  xm[b*U_ + u] = s * (1.f/(float)T_);
}

// ---------------- MLP head ----------------
__global__ __launch_bounds__(128) void head_kernel(
    const float* __restrict__ xm, const float* __restrict__ other,
    const float* __restrict__ m1W, const float* __restrict__ m1b,
    const float* __restrict__ l1s, const float* __restrict__ l1b,
    const float* __restrict__ m2W, const float* __restrict__ m2b,
    const float* __restrict__ l2s, const float* __restrict__ l2b,
    const float* __restrict__ oW,  const float* __restrict__ ob,
    float* __restrict__ outp)
{
  __shared__ float c[320];
  __shared__ float h1[128];
  __shared__ float sb[2];
  int b = blockIdx.x, tid = threadIdx.x;
  c[tid]       = xm[b*256 + tid];
  c[tid + 128] = xm[b*256 + tid + 128];
  if (tid < 64) c[256 + tid] = other[b*64 + tid];
  __syncthreads();
  float s = m1b[tid];
  for (int i = 0; i < 320; ++i) s += c[i] * m1W[i*128 + tid];
  s = fmaxf(s, 0.f);
  float m = s;
  for (int o = 32; o; o >>= 1) m += __shfl_xor(m, o);
  if ((tid & 63) == 0) sb[tid >> 6] = m;
  __syncthreads();
  m = (sb[0] + sb[1]) * (1.f/128.f);
  __syncthreads();
  float d = s - m, var = d*d;
  for (int o = 32; o; o >>= 1) var += __shfl_xor(var, o);
  if ((tid & 63) == 0) sb[tid >> 6] = var;
  __syncthreads();
  var = (sb[0] + sb[1]) * (1.f/128.f);
  h1[tid] = d * rsqrtf(var + EPSF) * l1s[tid] + l1b[tid];
  __syncthreads();
  if (tid < 64) {
    float s2 = m2b[tid];
    for (int i = 0; i < 128; ++i) s2 += h1[i] * m2W[i*64 + tid];
    s2 = fmaxf(s2, 0.f);
    float m2 = s2;
    for (int o = 32; o; o >>= 1) m2 += __shfl_xor(m2, o);
    m2 *= (1.f/64.f);
    float d2 = s2 - m2, v2 = d2*d2;
    for (int o = 32; o; o >>= 1) v2 += __shfl_xor(v2, o);
    v2 *= (1.f/64.f);
    float h2v = d2 * rsqrtf(v2 + EPSF) * l2s[tid] + l2b[tid];
    float y = h2v * oW[tid];
    for (int o = 32; o; o >>= 1) y += __shfl_xor(y, o);
    if (tid == 0) outp[b] = y + ob[0];
  }
}

// ---------------- host ----------------
extern "C" void kernel_launch(void* const* d_in, const int* in_sizes, int n_in,
                              void* d_out, int out_size, void* d_ws, size_t ws_size,
                              hipStream_t stream)
{
  const float* cgm   = (const float*)d_in[0];
  const float* other = (const float*)d_in[1];
  const float* d0_W  = (const float*)d_in[2];
  const float* d0_b  = (const float*)d_in[3];
  const float* ln0_s = (const float*)d_in[4];
  const float* ln0_b = (const float*)d_in[5];
  const float* gWi   = (const float*)d_in[6];
  const float* gbi   = (const float*)d_in[7];
  const float* gWh   = (const float*)d_in[8];
  const float* gbhn  = (const float*)d_in[9];
  const float* ln1_s = (const float*)d_in[10];
  const float* ln1_b = (const float*)d_in[11];
  const float* Wq    = (const float*)d_in[12];
  const float* bq    = (const float*)d_in[13];
  const float* Wk    = (const float*)d_in[14];
  const float* bk    = (const float*)d_in[15];
  const float* Wv    = (const float*)d_in[16];
  const float* bv    = (const float*)d_in[17];
  const float* Wo    = (const float*)d_in[18];
  const float* bo    = (const float*)d_in[19];
  const float* ln2_s = (const float*)d_in[20];
  const float* ln2_b = (const float*)d_in[21];
  const float* m1W   = (const float*)d_in[22];
  const float* m1b   = (const float*)d_in[23];
  const float* l1s   = (const float*)d_in[24];
  const float* l1b   = (const float*)d_in[25];
  const float* m2W   = (const float*)d_in[26];
  const float* m2b   = (const float*)d_in[27];
  const float* l2s   = (const float*)d_in[28];
  const float* l2b   = (const float*)d_in[29];
  const float* oW    = (const float*)d_in[30];
  const float* ob    = (const float*)d_in[31];
  float* out = (float*)d_out;
  (void)in_sizes; (void)n_in; (void)out_size; (void)ws_size;

  // workspace — ALL REGIONS DISJOINT (no aliasing). ~228 MB total.
  char* p = (char*)d_ws;
  float*     d0out = (float*)p;    p += 37748736;   // [MT,256] f32 (d0 GEMM out)
  _Float16*  xgh   = (_Float16*)p; p += 56623104;   // [MT,768] f16 (GRU gate input)
  _Float16*  qkvh  = (_Float16*)p; p += 56623104;   // [MT,768] f16
  _Float16*  aoh   = (_Float16*)p; p += 18874368;   // [MT,256] f16
  float*     x     = (float*)p;    p += 37748736;   // [MT,256] f32 residual
  _Float16*  xh    = (_Float16*)p; p += 18874368;   // [MT,256] f16 residual
  _Float16*  wiT   = (_Float16*)p; p += 786432;     // [2][768*256]
  _Float16*  qkvT  = (_Float16*)p; p += 786432;
  _Float16*  woT   = (_Float16*)p; p += 262144;
  float*     bqkv  = (float*)p;    p += 6144;
  float*     xmean = (float*)p;    p += 131072;
  float*     gbuf  = d0out;   // [MT,256] f32 — reuse d0out region (d0out dead after ln0)

  for (int i = 0; i < 2; ++i) {
    tconv_kernel<<<(256*768+255)/256, 256, 0, stream>>>(gWi + (long)i*196608, wiT + (long)i*196608, 256, 768);
    tconv_kernel<<<(256*256+255)/256, 256, 0, stream>>>(Wq + (long)i*65536, qkvT + (long)i*196608,          256, 256);
    tconv_kernel<<<(256*256+255)/256, 256, 0, stream>>>(Wk + (long)i*65536, qkvT + (long)i*196608 + 65536,  256, 256);
    tconv_kernel<<<(256*256+255)/256, 256, 0, stream>>>(Wv + (long)i*65536, qkvT + (long)i*196608 + 131072, 256, 256);
    tconv_kernel<<<(256*256+255)/256, 256, 0, stream>>>(Wo + (long)i*65536, woT + (long)i*65536, 256, 256);
    catbias_kernel<<<3, 256, 0, stream>>>(bq + i*256, bk + i*256, bv + i*256, bqkv + i*768);
  }

  {
    dim3 g0(4, 576);
    gemm_f32_kernel<<<g0, 256, 0, stream>>>(cgm, d0_W, d0out, d0_b, MT, 256, 16, 16, 256, 256);
  }
  ln256_kernel<<<MT, 256, 0, stream>>>(d0out, nullptr, nullptr, ln0_s, ln0_b, x, xh);

  for (int i = 0; i < 2; ++i) {
    // xg = x @ Wi + bi  (f16 out)
    {
      dim3 g1(6, 288);
      gemm_bt_f16_kernel<1><<<g1, 256, 0, stream>>>(xh, wiT + (long)i*196608, nullptr, xgh,
                                                    gbi + i*768, MT, 768, 256);
    }
    gru_scan_kernel<<<128, 1024, 0, stream>>>(xgh, gWh + (long)i*196608, gbhn + i*256, gbuf);
    ln256_kernel<<<MT, 256, 0, stream>>>(gbuf, nullptr, x, ln1_s + i*256, ln1_b + i*256, x, xh);
    // qkv (f16 out)
    {
      dim3 g2(6, 288);
      gemm_bt_f16_kernel<1><<<g2, 256, 0, stream>>>(xh, qkvT + (long)i*196608, nullptr, qkvh,
                                                    bqkv + i*768, MT, 768, 256);
    }
    attn_simple_kernel<<<2048, 256, 0, stream>>>(qkvh, aoh);
    // wo_out = ao @ Wo + bo (f32 into gbuf); x = LN(wo_out + x)
    {
      dim3 g3(2, 288);
      gemm_bt_f16_kernel<0><<<g3, 256, 0, stream>>>(aoh, woT + (long)i*65536, gbuf, nullptr,
                                                    bo + i*256, MT, 256, 256);
    }
    ln256_kernel<<<MT, 256, 0, stream>>>(gbuf, x, nullptr, ln2_s + i*256, ln2_b + i*256, x, xh);
  }

  meanT_kernel<<<128, 256, 0, stream>>>(x, xmean);
  head_kernel<<<128, 128, 0, stream>>>(xmean, other, m1W, m1b, l1s, l1b,
                                       m2W, m2b, l2s, l2b, oW, ob, out);
}